// Round 1
// baseline (420.789 us; speedup 1.0000x reference)
//
#include <hip/hip_runtime.h>

#define B_SZ 4
#define C_IN 256
#define H_IMG 64
#define W_IMG 64
#define HWSZ (H_IMG * W_IMG)
#define NOFF 18
#define NK 9
#define NG 4
#define CG 64

// ---------------------------------------------------------------------------
// K0: transpose w_deform (256,64,3,3) -> wT[g][k][i][o]  (coalesced re-stage)
// ---------------------------------------------------------------------------
__global__ __launch_bounds__(256)
void transpose_wd_kernel(const float* __restrict__ wd, float* __restrict__ wT) {
    int idx = blockIdx.x * 256 + threadIdx.x;
    if (idx >= C_IN * CG * NK) return;
    int k  = idx % NK;
    int i  = (idx / NK) % CG;
    int co = idx / (NK * CG);
    int g = co >> 6, o = co & 63;
    wT[((g * NK + k) * CG + i) * CG + o] = wd[idx];
}

// ---------------------------------------------------------------------------
// K1: offset conv: off[b,co,oy,ox] = b_off[co] + sum_{c,3x3} w_off[co,c,..]*x
// block = (b, co, oy4); 256 threads = 4 oy rows x 64 ox
// ---------------------------------------------------------------------------
__global__ __launch_bounds__(256)
void off_conv_kernel(const float* __restrict__ x, const float* __restrict__ w_off,
                     const float* __restrict__ b_off, float* __restrict__ off) {
    __shared__ float wsm[C_IN * NK];  // 9216 B, this block's co slice
    int bid = blockIdx.x;
    int oy4 = bid & 15;
    int co  = (bid >> 4) % NOFF;
    int b   = bid / (16 * NOFF);
    for (int e = threadIdx.x; e < C_IN * NK; e += 256)
        wsm[e] = w_off[co * C_IN * NK + e];
    __syncthreads();
    int ox = threadIdx.x & 63;
    int oy = oy4 * 4 + (threadIdx.x >> 6);   // wave-uniform
    const float* xb = x + (size_t)b * C_IN * HWSZ;
    float acc = b_off[co];
    for (int c = 0; c < C_IN; ++c) {
        const float* xc = xb + c * HWSZ;
        const float* wc = wsm + c * NK;
        #pragma unroll
        for (int dy = 0; dy < 3; ++dy) {
            int y = oy + dy - 1;
            if ((unsigned)y >= (unsigned)H_IMG) continue;  // wave-uniform branch
            const float* xr = xc + y * W_IMG;
            #pragma unroll
            for (int dx = 0; dx < 3; ++dx) {
                int xx = ox + dx - 1;
                float xv = ((unsigned)xx < (unsigned)W_IMG) ? xr[xx] : 0.f;
                acc = fmaf(wc[dy * 3 + dx], xv, acc);
            }
        }
    }
    off[(b * NOFF + co) * HWSZ + oy * W_IMG + ox] = acc;
}

// ---------------------------------------------------------------------------
// K2: fused bilinear sampling + grouped conv.
// block = (b, g, oy).  Output tile: 64 o-channels x 64 ox.
// Phase A: sampling info per (k, ox) -> LDS (indices + validity-masked wts).
// Per k: stage w[64i][64o] + val[64i][64ox] in LDS, 4x4 register outer-product.
// ---------------------------------------------------------------------------
__global__ __launch_bounds__(256)
void deform_main_kernel(const float* __restrict__ x, const float* __restrict__ off,
                        const float* __restrict__ wT, float* __restrict__ out) {
    __shared__ int4   sidx[NK * 64];    // 9216 B
    __shared__ float4 swt [NK * 64];    // 9216 B
    __shared__ float  wlds[CG * 64];    // 16384 B  [i][o]
    __shared__ float  vlds[CG * 64];    // 16384 B  [i][ox]

    int bid = blockIdx.x;
    int oy = bid & 63;
    int g  = (bid >> 6) & 3;
    int b  = bid >> 8;
    int tid = threadIdx.x;

    // ---- Phase A: sampling metadata ----
    for (int e = tid; e < NK * 64; e += 256) {
        int k = e >> 6, ox = e & 63;
        int ki = k / 3, kj = k % 3;
        float offy = off[(b * NOFF + 2 * k)     * HWSZ + oy * W_IMG + ox];
        float offx = off[(b * NOFF + 2 * k + 1) * HWSZ + oy * W_IMG + ox];
        float py = (float)(oy - 1 + ki) + offy;
        float px = (float)(ox - 1 + kj) + offx;
        float y0 = floorf(py), x0 = floorf(px);
        float wy1 = py - y0, wx1 = px - x0;
        float wy0 = 1.f - wy1, wx0 = 1.f - wx1;
        float y1 = y0 + 1.f, x1 = x0 + 1.f;
        bool vy0 = (y0 >= 0.f) && (y0 <= 63.f);
        bool vy1 = (y1 >= 0.f) && (y1 <= 63.f);
        bool vx0 = (x0 >= 0.f) && (x0 <= 63.f);
        bool vx1 = (x1 >= 0.f) && (x1 <= 63.f);
        int iy0 = (int)fminf(fmaxf(y0, 0.f), 63.f);
        int iy1 = (int)fminf(fmaxf(y1, 0.f), 63.f);
        int ix0 = (int)fminf(fmaxf(x0, 0.f), 63.f);
        int ix1 = (int)fminf(fmaxf(x1, 0.f), 63.f);
        sidx[e] = make_int4(iy0 * W_IMG + ix0, iy0 * W_IMG + ix1,
                            iy1 * W_IMG + ix0, iy1 * W_IMG + ix1);
        swt[e] = make_float4(vy0 && vx0 ? wy0 * wx0 : 0.f,
                             vy0 && vx1 ? wy0 * wx1 : 0.f,
                             vy1 && vx0 ? wy1 * wx0 : 0.f,
                             vy1 && vx1 ? wy1 * wx1 : 0.f);
    }

    int oxl   = tid & 63;          // this thread's sampling column
    int wid   = tid >> 6;          // wave id 0..3
    int ox0   = (tid & 15) * 4;    // output ox quad
    int obase = (tid >> 4) * 4;    // output o quad
    float acc[4][4] = {{0.f, 0.f, 0.f, 0.f}};

    const float* xg  = x  + (size_t)(b * C_IN + g * CG) * HWSZ;
    const float* wTg = wT + (size_t)g * NK * CG * 64;

    for (int k = 0; k < NK; ++k) {
        __syncthreads();  // prev GEMM reads done (and Phase A done at k=0)
        // stage weight slice wT[g][k][i][o] -> wlds  (coalesced float4)
        {
            const float4* src = (const float4*)(wTg + k * CG * 64);
            float4* dst = (float4*)wlds;
            for (int e = tid; e < CG * 16; e += 256) dst[e] = src[e];
        }
        // stage val slice: bilinear gather, 16 (i,ox) entries per thread
        {
            int4   id4 = sidx[k * 64 + oxl];
            float4 wt4 = swt [k * 64 + oxl];
            #pragma unroll
            for (int j = 0; j < 16; ++j) {
                int i = 4 * j + wid;              // wave-uniform channel
                const float* xc = xg + i * HWSZ;
                float v = wt4.x * xc[id4.x] + wt4.y * xc[id4.y]
                        + wt4.z * xc[id4.z] + wt4.w * xc[id4.w];
                vlds[i * 64 + oxl] = v;
            }
        }
        __syncthreads();
        // 4x4 register outer-product: acc[o][x] += w[o,i] * v[i,x]
        #pragma unroll 8
        for (int i = 0; i < 64; ++i) {
            float4 v  = *(const float4*)&vlds[i * 64 + ox0];
            float4 w4 = *(const float4*)&wlds[i * 64 + obase];
            acc[0][0] = fmaf(w4.x, v.x, acc[0][0]);
            acc[0][1] = fmaf(w4.x, v.y, acc[0][1]);
            acc[0][2] = fmaf(w4.x, v.z, acc[0][2]);
            acc[0][3] = fmaf(w4.x, v.w, acc[0][3]);
            acc[1][0] = fmaf(w4.y, v.x, acc[1][0]);
            acc[1][1] = fmaf(w4.y, v.y, acc[1][1]);
            acc[1][2] = fmaf(w4.y, v.z, acc[1][2]);
            acc[1][3] = fmaf(w4.y, v.w, acc[1][3]);
            acc[2][0] = fmaf(w4.z, v.x, acc[2][0]);
            acc[2][1] = fmaf(w4.z, v.y, acc[2][1]);
            acc[2][2] = fmaf(w4.z, v.z, acc[2][2]);
            acc[2][3] = fmaf(w4.z, v.w, acc[2][3]);
            acc[3][0] = fmaf(w4.w, v.x, acc[3][0]);
            acc[3][1] = fmaf(w4.w, v.y, acc[3][1]);
            acc[3][2] = fmaf(w4.w, v.z, acc[3][2]);
            acc[3][3] = fmaf(w4.w, v.w, acc[3][3]);
        }
    }

    // epilogue: coalesced float4 stores
    float* outb = out + (size_t)(b * C_IN + g * CG) * HWSZ + oy * W_IMG;
    #pragma unroll
    for (int a = 0; a < 4; ++a) {
        float4 r = make_float4(acc[a][0], acc[a][1], acc[a][2], acc[a][3]);
        *(float4*)&outb[(obase + a) * HWSZ + ox0] = r;
    }
}

// ---------------------------------------------------------------------------
extern "C" void kernel_launch(void* const* d_in, const int* in_sizes, int n_in,
                              void* d_out, int out_size, void* d_ws, size_t ws_size,
                              hipStream_t stream) {
    const float* x        = (const float*)d_in[0];
    const float* w_off    = (const float*)d_in[1];
    const float* b_off    = (const float*)d_in[2];
    const float* w_deform = (const float*)d_in[3];
    float* out = (float*)d_out;

    // ws layout: off buffer (B*18*4096 floats = 1.18 MB) then wT (147456 floats)
    float* off = (float*)d_ws;
    float* wT  = off + (size_t)B_SZ * NOFF * HWSZ;

    transpose_wd_kernel<<<(C_IN * CG * NK + 255) / 256, 256, 0, stream>>>(w_deform, wT);
    off_conv_kernel<<<B_SZ * NOFF * 16, 256, 0, stream>>>(x, w_off, b_off, off);
    deform_main_kernel<<<B_SZ * NG * H_IMG, 256, 0, stream>>>(x, off, wT, out);
}

// Round 3
// 293.565 us; speedup vs baseline: 1.4334x; 1.4334x over previous
//
#include <hip/hip_runtime.h>

#define B_SZ 4
#define C_IN 256
#define H_IMG 64
#define W_IMG 64
#define HWSZ (H_IMG * W_IMG)
#define NOFF 18
#define NK 9
#define NG 4
#define CG 64

// ---------------------------------------------------------------------------
// K0: transpose w_deform (256,64,3,3) -> wT[g][k][i][o]  (coalesced re-stage)
// ---------------------------------------------------------------------------
__global__ __launch_bounds__(256)
void transpose_wd_kernel(const float* __restrict__ wd, float* __restrict__ wT) {
    int idx = blockIdx.x * 256 + threadIdx.x;
    if (idx >= C_IN * CG * NK) return;
    int k  = idx % NK;
    int i  = (idx / NK) % CG;
    int co = idx / (NK * CG);
    int g = co >> 6, o = co & 63;
    wT[((g * NK + k) * CG + i) * CG + o] = wd[idx];
}

// ---------------------------------------------------------------------------
// K1 v2: offset conv as LDS-tiled multi-channel accumulation.
// block = (b, oy); 512 threads = 8 waves; thread = one ox pixel, 18 acc VGPRs.
// Per 64-channel chunk: stage x[64ch][3rows][68cols] in LDS; wave w owns 8
// channels of the chunk (w*8..w*8+7), so each thread covers 32 channels total.
// Weights are wave-uniform -> s_load (scalar pipe, zero VALU cost).
// 9 LDS reads amortized over 162 FMAs per channel.  Epilogue: 8-way LDS
// reduction + bias.
// ---------------------------------------------------------------------------
__global__ __launch_bounds__(512)
void off_conv_kernel(const float* __restrict__ x, const float* __restrict__ w_off,
                     const float* __restrict__ b_off, float* __restrict__ off) {
    __shared__ float xs[CG * 3 * 68];   // 52224 B; reused as rsum[8][18][64]
    int bid = blockIdx.x;
    int oy = bid & 63;
    int b  = bid >> 6;
    int tid = threadIdx.x;
    int q  = __builtin_amdgcn_readfirstlane(tid >> 6);  // wave id 0..7 (SGPR)
    int ox = tid & 63;

    float acc[NOFF];
    #pragma unroll
    for (int co = 0; co < NOFF; ++co) acc[co] = 0.f;

    for (int chunk = 0; chunk < 4; ++chunk) {
        __syncthreads();   // previous chunk's LDS reads complete
        // stage: channels [chunk*64, chunk*64+64) x rows (oy-1..oy+1) x cols (-1..66)
        for (int e = tid; e < CG * 3 * 68; e += 512) {
            int ch  = e / (3 * 68);
            int r   = (e / 68) % 3;
            int col = e % 68;
            int y  = oy + r - 1;
            int xx = col - 1;
            float v = 0.f;
            if ((unsigned)y < (unsigned)H_IMG && (unsigned)xx < (unsigned)W_IMG)
                v = x[(((size_t)b * C_IN + chunk * CG + ch) * H_IMG + y) * W_IMG + xx];
            xs[e] = v;
        }
        __syncthreads();
        // compute: this wave's 8 channels of the chunk
        for (int j = 0; j < 8; ++j) {
            int ch = q * 8 + j;                       // wave-uniform
            const float* xp = &xs[(ch * 3) * 68 + ox];
            float xv[9];
            #pragma unroll
            for (int r = 0; r < 3; ++r) {
                xv[r * 3 + 0] = xp[r * 68 + 0];
                xv[r * 3 + 1] = xp[r * 68 + 1];
                xv[r * 3 + 2] = xp[r * 68 + 2];
            }
            int c = chunk * CG + ch;                  // wave-uniform channel
            const float* wp = w_off + (size_t)c * NK; // w_off[co][c][tap]
            #pragma unroll
            for (int co = 0; co < NOFF; ++co) {
                const float* w = wp + (size_t)co * C_IN * NK;  // uniform -> s_load
                float a = acc[co];
                a = fmaf(w[0], xv[0], a);
                a = fmaf(w[1], xv[1], a);
                a = fmaf(w[2], xv[2], a);
                a = fmaf(w[3], xv[3], a);
                a = fmaf(w[4], xv[4], a);
                a = fmaf(w[5], xv[5], a);
                a = fmaf(w[6], xv[6], a);
                a = fmaf(w[7], xv[7], a);
                a = fmaf(w[8], xv[8], a);
                acc[co] = a;
            }
        }
    }

    // epilogue: 8-way cross-wave reduction through LDS (reuse xs)
    __syncthreads();
    float* rsum = xs;                      // [8][18][64] = 4608 floats
    #pragma unroll
    for (int co = 0; co < NOFF; ++co)
        rsum[(q * NOFF + co) * 64 + ox] = acc[co];
    __syncthreads();
    for (int e = tid; e < NOFF * 64; e += 512) {
        int co  = e >> 6;
        int oxx = e & 63;
        float v = b_off[co];
        #pragma unroll
        for (int w = 0; w < 8; ++w)
            v += rsum[(w * NOFF + co) * 64 + oxx];
        off[((size_t)b * NOFF + co) * HWSZ + oy * W_IMG + oxx] = v;
    }
}

// ---------------------------------------------------------------------------
// K2: fused bilinear sampling + grouped conv.  (unchanged this round)
// block = (b, g, oy).  Output tile: 64 o-channels x 64 ox.
// ---------------------------------------------------------------------------
__global__ __launch_bounds__(256)
void deform_main_kernel(const float* __restrict__ x, const float* __restrict__ off,
                        const float* __restrict__ wT, float* __restrict__ out) {
    __shared__ int4   sidx[NK * 64];    // 9216 B
    __shared__ float4 swt [NK * 64];    // 9216 B
    __shared__ float  wlds[CG * 64];    // 16384 B  [i][o]
    __shared__ float  vlds[CG * 64];    // 16384 B  [i][ox]

    int bid = blockIdx.x;
    int oy = bid & 63;
    int g  = (bid >> 6) & 3;
    int b  = bid >> 8;
    int tid = threadIdx.x;

    // ---- Phase A: sampling metadata ----
    for (int e = tid; e < NK * 64; e += 256) {
        int k = e >> 6, ox = e & 63;
        int ki = k / 3, kj = k % 3;
        float offy = off[(b * NOFF + 2 * k)     * HWSZ + oy * W_IMG + ox];
        float offx = off[(b * NOFF + 2 * k + 1) * HWSZ + oy * W_IMG + ox];
        float py = (float)(oy - 1 + ki) + offy;
        float px = (float)(ox - 1 + kj) + offx;
        float y0 = floorf(py), x0 = floorf(px);
        float wy1 = py - y0, wx1 = px - x0;
        float wy0 = 1.f - wy1, wx0 = 1.f - wx1;
        float y1 = y0 + 1.f, x1 = x0 + 1.f;
        bool vy0 = (y0 >= 0.f) && (y0 <= 63.f);
        bool vy1 = (y1 >= 0.f) && (y1 <= 63.f);
        bool vx0 = (x0 >= 0.f) && (x0 <= 63.f);
        bool vx1 = (x1 >= 0.f) && (x1 <= 63.f);
        int iy0 = (int)fminf(fmaxf(y0, 0.f), 63.f);
        int iy1 = (int)fminf(fmaxf(y1, 0.f), 63.f);
        int ix0 = (int)fminf(fmaxf(x0, 0.f), 63.f);
        int ix1 = (int)fminf(fmaxf(x1, 0.f), 63.f);
        sidx[e] = make_int4(iy0 * W_IMG + ix0, iy0 * W_IMG + ix1,
                            iy1 * W_IMG + ix0, iy1 * W_IMG + ix1);
        swt[e] = make_float4(vy0 && vx0 ? wy0 * wx0 : 0.f,
                             vy0 && vx1 ? wy0 * wx1 : 0.f,
                             vy1 && vx0 ? wy1 * wx0 : 0.f,
                             vy1 && vx1 ? wy1 * wx1 : 0.f);
    }

    int oxl   = tid & 63;          // this thread's sampling column
    int wid   = tid >> 6;          // wave id 0..3
    int ox0   = (tid & 15) * 4;    // output ox quad
    int obase = (tid >> 4) * 4;    // output o quad
    float acc[4][4] = {{0.f, 0.f, 0.f, 0.f}};

    const float* xg  = x  + (size_t)(b * C_IN + g * CG) * HWSZ;
    const float* wTg = wT + (size_t)g * NK * CG * 64;

    for (int k = 0; k < NK; ++k) {
        __syncthreads();  // prev GEMM reads done (and Phase A done at k=0)
        // stage weight slice wT[g][k][i][o] -> wlds  (coalesced float4)
        {
            const float4* src = (const float4*)(wTg + k * CG * 64);
            float4* dst = (float4*)wlds;
            for (int e = tid; e < CG * 16; e += 256) dst[e] = src[e];
        }
        // stage val slice: bilinear gather, 16 (i,ox) entries per thread
        {
            int4   id4 = sidx[k * 64 + oxl];
            float4 wt4 = swt [k * 64 + oxl];
            #pragma unroll
            for (int j = 0; j < 16; ++j) {
                int i = 4 * j + wid;              // wave-uniform channel
                const float* xc = xg + i * HWSZ;
                float v = wt4.x * xc[id4.x] + wt4.y * xc[id4.y]
                        + wt4.z * xc[id4.z] + wt4.w * xc[id4.w];
                vlds[i * 64 + oxl] = v;
            }
        }
        __syncthreads();
        // 4x4 register outer-product: acc[o][x] += w[o,i] * v[i,x]
        #pragma unroll 8
        for (int i = 0; i < 64; ++i) {
            float4 v  = *(const float4*)&vlds[i * 64 + ox0];
            float4 w4 = *(const float4*)&wlds[i * 64 + obase];
            acc[0][0] = fmaf(w4.x, v.x, acc[0][0]);
            acc[0][1] = fmaf(w4.x, v.y, acc[0][1]);
            acc[0][2] = fmaf(w4.x, v.z, acc[0][2]);
            acc[0][3] = fmaf(w4.x, v.w, acc[0][3]);
            acc[1][0] = fmaf(w4.y, v.x, acc[1][0]);
            acc[1][1] = fmaf(w4.y, v.y, acc[1][1]);
            acc[1][2] = fmaf(w4.y, v.z, acc[1][2]);
            acc[1][3] = fmaf(w4.y, v.w, acc[1][3]);
            acc[2][0] = fmaf(w4.z, v.x, acc[2][0]);
            acc[2][1] = fmaf(w4.z, v.y, acc[2][1]);
            acc[2][2] = fmaf(w4.z, v.z, acc[2][2]);
            acc[2][3] = fmaf(w4.z, v.w, acc[2][3]);
            acc[3][0] = fmaf(w4.w, v.x, acc[3][0]);
            acc[3][1] = fmaf(w4.w, v.y, acc[3][1]);
            acc[3][2] = fmaf(w4.w, v.z, acc[3][2]);
            acc[3][3] = fmaf(w4.w, v.w, acc[3][3]);
        }
    }

    // epilogue: coalesced float4 stores
    float* outb = out + (size_t)(b * C_IN + g * CG) * HWSZ + oy * W_IMG;
    #pragma unroll
    for (int a = 0; a < 4; ++a) {
        float4 r = make_float4(acc[a][0], acc[a][1], acc[a][2], acc[a][3]);
        *(float4*)&outb[(obase + a) * HWSZ + ox0] = r;
    }
}

// ---------------------------------------------------------------------------
extern "C" void kernel_launch(void* const* d_in, const int* in_sizes, int n_in,
                              void* d_out, int out_size, void* d_ws, size_t ws_size,
                              hipStream_t stream) {
    const float* x        = (const float*)d_in[0];
    const float* w_off    = (const float*)d_in[1];
    const float* b_off    = (const float*)d_in[2];
    const float* w_deform = (const float*)d_in[3];
    float* out = (float*)d_out;

    // ws layout: off buffer (B*18*4096 floats = 1.18 MB) then wT (147456 floats)
    float* off = (float*)d_ws;
    float* wT  = off + (size_t)B_SZ * NOFF * HWSZ;

    transpose_wd_kernel<<<(C_IN * CG * NK + 255) / 256, 256, 0, stream>>>(w_deform, wT);
    off_conv_kernel<<<B_SZ * H_IMG, 512, 0, stream>>>(x, w_off, b_off, off);
    deform_main_kernel<<<B_SZ * NG * H_IMG, 256, 0, stream>>>(x, off, wT, out);
}

// Round 4
// 214.127 us; speedup vs baseline: 1.9651x; 1.3710x over previous
//
#include <hip/hip_runtime.h>

#define B_SZ 4
#define C_IN 256
#define H_IMG 64
#define W_IMG 64
#define HWSZ 4096
#define NOFF 18
#define NK 9
#define NG 4
#define CG 64

typedef short s16x8 __attribute__((ext_vector_type(8)));
typedef float f32x4 __attribute__((ext_vector_type(4)));

__device__ __forceinline__ unsigned short f2bf(float f) {
    union { float f; unsigned u; } v; v.f = f;
    unsigned r = v.u + 0x7FFFu + ((v.u >> 16) & 1u);   // RNE
    return (unsigned short)(r >> 16);
}
__device__ __forceinline__ unsigned pk(unsigned short lo, unsigned short hi) {
    return (unsigned)lo | ((unsigned)hi << 16);
}
// XOR-swizzle within a 128B LDS row: kills the 32-way same-bank column conflict (T2/G4)
#define SW(row, byteoff) ((byteoff) ^ (((row) & 7) << 4))

// ---------------------------------------------------------------------------
// K0a: w_off (18,256,3,3) -> wA bf16 [tap][co(pad32)][c]   (A-operand layout)
// ---------------------------------------------------------------------------
__global__ __launch_bounds__(256)
void prep_woff_kernel(const float* __restrict__ w_off, unsigned short* __restrict__ wA) {
    int idx = blockIdx.x * 256 + threadIdx.x;        // 9*32*256 = 73728
    if (idx >= NK * 32 * C_IN) return;
    int c   = idx & 255;
    int co  = (idx >> 8) & 31;
    int tap = idx >> 13;
    float v = (co < NOFF) ? w_off[(co * C_IN + c) * NK + tap] : 0.f;
    wA[idx] = f2bf(v);
}

// ---------------------------------------------------------------------------
// K0b: w_deform (256,64,3,3) -> wB2 bf16 [g][k][o][i]      (A-operand layout)
// ---------------------------------------------------------------------------
__global__ __launch_bounds__(256)
void prep_wdef_kernel(const float* __restrict__ wd, unsigned short* __restrict__ wB2) {
    int idx = blockIdx.x * 256 + threadIdx.x;        // 4*9*64*64 = 147456
    if (idx >= NG * NK * CG * CG) return;
    int i = idx & 63;
    int o = (idx >> 6) & 63;
    int k = (idx >> 12) % NK;
    int g = idx / (CG * CG * NK);
    wB2[idx] = f2bf(wd[((g * CG + o) * CG + i) * NK + k]);
}

// ---------------------------------------------------------------------------
// K1: offset conv via MFMA.  block=(b,oy), 256 thr = 4 waves.
// C[32co(pad)][64ox] = sum over 9 taps x 4 c-chunks of A[32][64c] * B[64c][64ox]
// B staged by shifted coalesced loads (lane = ox), A from wA.
// ---------------------------------------------------------------------------
__global__ __launch_bounds__(256)
void off_conv_mfma(const float* __restrict__ x, const unsigned short* __restrict__ wA,
                   const float* __restrict__ b_off, float* __restrict__ off) {
    __shared__ uint4 aS[256];   // 4 KB  A tile [32co][64c] bf16, swizzled rows
    __shared__ uint4 bS[512];   // 8 KB  B tile [64ox][64c] bf16, swizzled rows

    int bid = blockIdx.x;
    int oy = bid & 63;
    int b  = bid >> 6;
    int tid = threadIdx.x;
    int w  = tid >> 6;          // wave id
    int l  = tid & 63;          // lane

    int p_st  = tid & 63;       // staging: this thread's ox column
    int cg    = tid >> 6;       // staging: c-group (16 c's)
    int a_co  = tid >> 3;       // A staging row
    int a_j   = tid & 7;        // A staging 16B slot

    f32x4 acc[2] = {{0.f,0.f,0.f,0.f},{0.f,0.f,0.f,0.f}};
    const char* aC = (const char*)aS;
    const char* bC = (const char*)bS;

    for (int tap = 0; tap < NK; ++tap) {
        int dy = tap / 3 - 1, dx = tap % 3 - 1;
        int y = oy + dy;
        bool vy = (unsigned)y < (unsigned)H_IMG;
        int xx = p_st + dx;
        bool vx = vy && ((unsigned)xx < (unsigned)W_IMG);
        for (int cc = 0; cc < 4; ++cc) {
            int cbase = cc * 64;
            __syncthreads();
            // stage A: 32x64 bf16 (4KB), one uint4/thread, coalesced
            {
                uint4 wv = *(const uint4*)(wA + ((tap * 32 + a_co) * C_IN + cbase + a_j * 8));
                *(uint4*)((char*)aS + SW(a_co, a_co * 128 + a_j * 16)) = wv;
            }
            // stage B: 16 shifted x loads (coalesced: lanes=consecutive ox, same c)
            {
                const float* xb = x + (((size_t)b * C_IN + cbase + cg * 16) * H_IMG + y) * W_IMG + xx;
                unsigned short us[16];
                #pragma unroll 16
                for (int e = 0; e < 16; ++e) {
                    float v = vx ? xb[e * HWSZ] : 0.f;
                    us[e] = f2bf(v);
                }
                uint4 q0 = make_uint4(pk(us[0],us[1]), pk(us[2],us[3]), pk(us[4],us[5]), pk(us[6],us[7]));
                uint4 q1 = make_uint4(pk(us[8],us[9]), pk(us[10],us[11]), pk(us[12],us[13]), pk(us[14],us[15]));
                *(uint4*)((char*)bS + SW(p_st, p_st * 128 + cg * 32))      = q0;
                *(uint4*)((char*)bS + SW(p_st, p_st * 128 + cg * 32 + 16)) = q1;
            }
            __syncthreads();
            // MFMA: wave w -> mt = w&1, ntiles {2*(w>>1), 2*(w>>1)+1}
            #pragma unroll
            for (int ks = 0; ks < 2; ++ks) {
                int kb = ks * 64 + (l >> 4) * 16;
                int ra = (w & 1) * 16 + (l & 15);
                s16x8 af = *(const s16x8*)(aC + SW(ra, ra * 128 + kb));
                #pragma unroll
                for (int t = 0; t < 2; ++t) {
                    int rb = (2 * (w >> 1) + t) * 16 + (l & 15);
                    s16x8 bf = *(const s16x8*)(bC + SW(rb, rb * 128 + kb));
                    acc[t] = __builtin_amdgcn_mfma_f32_16x16x32_bf16(af, bf, acc[t], 0, 0, 0);
                }
            }
        }
    }

    // epilogue: D row m=(l>>4)*4+r, col n=l&15 ; only co<18 stored
    #pragma unroll
    for (int t = 0; t < 2; ++t) {
        int px = (2 * (w >> 1) + t) * 16 + (l & 15);
        #pragma unroll
        for (int r = 0; r < 4; ++r) {
            int co = (w & 1) * 16 + (l >> 4) * 4 + r;
            if (co < NOFF)
                off[(((size_t)b * NOFF + co) * H_IMG + oy) * W_IMG + px] = acc[t][r] + b_off[co];
        }
    }
}

// ---------------------------------------------------------------------------
// K2: fused bilinear sampling + grouped conv via MFMA.  block=(b,g,oy).
// C[64o][64ox] = sum over 9 k of A[64o][64i] * B(val)[64i][64ox]
// ---------------------------------------------------------------------------
__global__ __launch_bounds__(256)
void deform_main_mfma(const float* __restrict__ x, const float* __restrict__ off,
                      const unsigned short* __restrict__ wB2, float* __restrict__ out) {
    __shared__ int4   sidx[NK * 64];   // 9216 B
    __shared__ float4 swt [NK * 64];   // 9216 B
    __shared__ uint4  aS[512];         // 8 KB  A [64o][64i] bf16, swizzled
    __shared__ uint4  bS[512];         // 8 KB  B [64ox][64i] bf16, swizzled

    int bid = blockIdx.x;
    int oy = bid & 63;
    int g  = (bid >> 6) & 3;
    int b  = bid >> 8;
    int tid = threadIdx.x;
    int w  = tid >> 6;
    int l  = tid & 63;

    // ---- Phase A: sampling metadata (fp32) ----
    for (int e = tid; e < NK * 64; e += 256) {
        int k = e >> 6, ox = e & 63;
        int ki = k / 3, kj = k % 3;
        float offy = off[((size_t)b * NOFF + 2 * k)     * HWSZ + oy * W_IMG + ox];
        float offx = off[((size_t)b * NOFF + 2 * k + 1) * HWSZ + oy * W_IMG + ox];
        float py = (float)(oy - 1 + ki) + offy;
        float px = (float)(ox - 1 + kj) + offx;
        float y0 = floorf(py), x0 = floorf(px);
        float wy1 = py - y0, wx1 = px - x0;
        float wy0 = 1.f - wy1, wx0 = 1.f - wx1;
        float y1 = y0 + 1.f, x1 = x0 + 1.f;
        bool vy0 = (y0 >= 0.f) && (y0 <= 63.f);
        bool vy1 = (y1 >= 0.f) && (y1 <= 63.f);
        bool vx0 = (x0 >= 0.f) && (x0 <= 63.f);
        bool vx1 = (x1 >= 0.f) && (x1 <= 63.f);
        int iy0 = (int)fminf(fmaxf(y0, 0.f), 63.f);
        int iy1 = (int)fminf(fmaxf(y1, 0.f), 63.f);
        int ix0 = (int)fminf(fmaxf(x0, 0.f), 63.f);
        int ix1 = (int)fminf(fmaxf(x1, 0.f), 63.f);
        sidx[e] = make_int4(iy0 * W_IMG + ix0, iy0 * W_IMG + ix1,
                            iy1 * W_IMG + ix0, iy1 * W_IMG + ix1);
        swt[e] = make_float4(vy0 && vx0 ? wy0 * wx0 : 0.f,
                             vy0 && vx1 ? wy0 * wx1 : 0.f,
                             vy1 && vx0 ? wy1 * wx0 : 0.f,
                             vy1 && vx1 ? wy1 * wx1 : 0.f);
    }

    int p_st = tid & 63;          // staging column (ox)
    int cg   = tid >> 6;          // staging i-group (16 i's)
    const float* xg = x + ((size_t)b * C_IN + g * CG) * HWSZ;
    const char* aC = (const char*)aS;
    const char* bC = (const char*)bS;

    f32x4 acc[2][2] = {{{0.f,0.f,0.f,0.f},{0.f,0.f,0.f,0.f}},
                       {{0.f,0.f,0.f,0.f},{0.f,0.f,0.f,0.f}}};

    for (int k = 0; k < NK; ++k) {
        __syncthreads();
        // stage A: wB2[g][k] 64x64 bf16 (8KB), two uint4/thread
        {
            int o = tid >> 2, j = (tid & 3) * 2;
            const unsigned short* src = wB2 + (((size_t)(g * NK + k) * CG + o) * CG + j * 8);
            uint4 v0 = *(const uint4*)src;
            uint4 v1 = *(const uint4*)(src + 8);
            *(uint4*)((char*)aS + SW(o, o * 128 + j * 16))        = v0;
            *(uint4*)((char*)aS + SW(o, o * 128 + j * 16 + 16))   = v1;
        }
        // stage B: bilinear gather, 16 vals (fixed ox, i = cg*16..+15)
        {
            int4   id4 = sidx[k * 64 + p_st];
            float4 wt4 = swt [k * 64 + p_st];
            const float* xc0 = xg + (size_t)(cg * 16) * HWSZ;
            unsigned short us[16];
            #pragma unroll 16
            for (int e = 0; e < 16; ++e) {
                const float* xc = xc0 + (size_t)e * HWSZ;
                float v = wt4.x * xc[id4.x] + wt4.y * xc[id4.y]
                        + wt4.z * xc[id4.z] + wt4.w * xc[id4.w];
                us[e] = f2bf(v);
            }
            uint4 q0 = make_uint4(pk(us[0],us[1]), pk(us[2],us[3]), pk(us[4],us[5]), pk(us[6],us[7]));
            uint4 q1 = make_uint4(pk(us[8],us[9]), pk(us[10],us[11]), pk(us[12],us[13]), pk(us[14],us[15]));
            *(uint4*)((char*)bS + SW(p_st, p_st * 128 + cg * 32))      = q0;
            *(uint4*)((char*)bS + SW(p_st, p_st * 128 + cg * 32 + 16)) = q1;
        }
        __syncthreads();
        // MFMA: wave owns mtiles {2*(w&1),+1} x ntiles {2*(w>>1),+1}
        #pragma unroll
        for (int ks = 0; ks < 2; ++ks) {
            int kb = ks * 64 + (l >> 4) * 16;
            s16x8 af[2], bf[2];
            #pragma unroll
            for (int i2 = 0; i2 < 2; ++i2) {
                int ra = (2 * (w & 1) + i2) * 16 + (l & 15);
                af[i2] = *(const s16x8*)(aC + SW(ra, ra * 128 + kb));
            }
            #pragma unroll
            for (int j2 = 0; j2 < 2; ++j2) {
                int rb = (2 * (w >> 1) + j2) * 16 + (l & 15);
                bf[j2] = *(const s16x8*)(bC + SW(rb, rb * 128 + kb));
            }
            #pragma unroll
            for (int i2 = 0; i2 < 2; ++i2)
                #pragma unroll
                for (int j2 = 0; j2 < 2; ++j2)
                    acc[i2][j2] = __builtin_amdgcn_mfma_f32_16x16x32_bf16(af[i2], bf[j2], acc[i2][j2], 0, 0, 0);
        }
    }

    // epilogue: D row m=(l>>4)*4+r (o), col n=l&15 (ox)
    #pragma unroll
    for (int i2 = 0; i2 < 2; ++i2) {
        int o0 = (2 * (w & 1) + i2) * 16 + (l >> 4) * 4;
        #pragma unroll
        for (int j2 = 0; j2 < 2; ++j2) {
            int px = (2 * (w >> 1) + j2) * 16 + (l & 15);
            float* ob = out + ((((size_t)b * C_IN + g * CG + o0) * H_IMG + oy) * W_IMG) + px;
            #pragma unroll
            for (int r = 0; r < 4; ++r)
                ob[(size_t)r * HWSZ] = acc[i2][j2][r];
        }
    }
}

// ---------------------------------------------------------------------------
extern "C" void kernel_launch(void* const* d_in, const int* in_sizes, int n_in,
                              void* d_out, int out_size, void* d_ws, size_t ws_size,
                              hipStream_t stream) {
    const float* x        = (const float*)d_in[0];
    const float* w_off    = (const float*)d_in[1];
    const float* b_off    = (const float*)d_in[2];
    const float* w_deform = (const float*)d_in[3];
    float* out = (float*)d_out;

    // ws layout (bytes): off fp32 [4*18*4096] = 1179648 | wA bf16 73728*2 | wB2 bf16 147456*2
    float* off = (float*)d_ws;
    unsigned short* wA  = (unsigned short*)((char*)d_ws + 1179648);
    unsigned short* wB2 = wA + NK * 32 * C_IN;

    prep_woff_kernel<<<(NK * 32 * C_IN + 255) / 256, 256, 0, stream>>>(w_off, wA);
    prep_wdef_kernel<<<(NG * NK * CG * CG + 255) / 256, 256, 0, stream>>>(w_deform, wB2);
    off_conv_mfma<<<B_SZ * H_IMG, 256, 0, stream>>>(x, wA, b_off, off);
    deform_main_mfma<<<B_SZ * NG * H_IMG, 256, 0, stream>>>(x, off, wB2, out);
}

// Round 5
// 159.017 us; speedup vs baseline: 2.6462x; 1.3466x over previous
//
#include <hip/hip_runtime.h>

#define B_SZ 4
#define C_IN 256
#define H_IMG 64
#define W_IMG 64
#define HWSZ 4096
#define NOFF 18
#define NK 9
#define NG 4
#define CG 64

typedef short s16x8 __attribute__((ext_vector_type(8)));
typedef float f32x4 __attribute__((ext_vector_type(4)));

__device__ __forceinline__ unsigned short f2bf(float f) {
    union { float f; unsigned u; } v; v.f = f;
    unsigned r = v.u + 0x7FFFu + ((v.u >> 16) & 1u);   // RNE
    return (unsigned short)(r >> 16);
}
__device__ __forceinline__ float bf2f(unsigned short u) {
    union { unsigned u; float f; } v; v.u = ((unsigned)u) << 16; return v.f;
}
__device__ __forceinline__ unsigned pk(unsigned short lo, unsigned short hi) {
    return (unsigned)lo | ((unsigned)hi << 16);
}
// XOR-swizzle: permute 16B slots within a row by the row id (T2/G4; measured 0 conflicts r4)
#define SW(row, byteoff) ((byteoff) ^ (((row) & 7) << 4))

// ---------------------------------------------------------------------------
// K0a: w_off (18,256,3,3) -> wA bf16 [tap][co(pad32)][c]   (A-operand layout)
// ---------------------------------------------------------------------------
__global__ __launch_bounds__(256)
void prep_woff_kernel(const float* __restrict__ w_off, unsigned short* __restrict__ wA) {
    int idx = blockIdx.x * 256 + threadIdx.x;        // 9*32*256 = 73728
    if (idx >= NK * 32 * C_IN) return;
    int c   = idx & 255;
    int co  = (idx >> 8) & 31;
    int tap = idx >> 13;
    float v = (co < NOFF) ? w_off[(co * C_IN + c) * NK + tap] : 0.f;
    wA[idx] = f2bf(v);
}

// ---------------------------------------------------------------------------
// K0b: w_deform (256,64,3,3) -> wB2 bf16 [g][k][o][i]      (A-operand layout)
// ---------------------------------------------------------------------------
__global__ __launch_bounds__(256)
void prep_wdef_kernel(const float* __restrict__ wd, unsigned short* __restrict__ wB2) {
    int idx = blockIdx.x * 256 + threadIdx.x;        // 4*9*64*64 = 147456
    if (idx >= NG * NK * CG * CG) return;
    int i = idx & 63;
    int o = (idx >> 6) & 63;
    int k = (idx >> 12) % NK;
    int g = idx / (CG * CG * NK);
    wB2[idx] = f2bf(wd[((g * CG + o) * CG + i) * NK + k]);
}

// ---------------------------------------------------------------------------
// K0c: x (b,c,y,x) fp32 -> xT bf16 [b][y][x][c]  (channel-last)
// block=(b,y), thread=c. Reads lane-strided (L1 line reuse across x), stores
// lane-contiguous. One (y,x)'s 64-ch group slice = exactly one 128B line.
// ---------------------------------------------------------------------------
__global__ __launch_bounds__(256)
void prep_xT_kernel(const float* __restrict__ x, unsigned short* __restrict__ xT) {
    int bid = blockIdx.x;
    int y = bid & 63, b = bid >> 6;
    int c = threadIdx.x;
    const float* src = x + (((size_t)b * C_IN + c) * H_IMG + y) * W_IMG;
    unsigned short* dst = xT + ((size_t)(b * H_IMG + y) * W_IMG) * C_IN + c;
    for (int xx = 0; xx < W_IMG; ++xx)
        dst[(size_t)xx * C_IN] = f2bf(src[xx]);
}

// ---------------------------------------------------------------------------
// K1 v3: offset conv via MFMA from channel-last xT.
// block=(b,oy), 512 thr = 8 waves, wave -> (mt=w&1, nt=w>>1).
// Per c-half(128): stage xs[3y][68x][128c] bf16 (52KB LDS, halo, swizzled),
// then 9 taps x 4 ks: A-frag from global wA (L2), B-frag = contiguous 16B LDS.
// ---------------------------------------------------------------------------
__global__ __launch_bounds__(512)
void off_conv_mfma(const unsigned short* __restrict__ xT, const unsigned short* __restrict__ wA,
                   const float* __restrict__ b_off, float* __restrict__ off) {
    __shared__ unsigned short xs[3 * 68 * 128];   // 52224 B
    int bid = blockIdx.x;
    int oy = bid & 63;
    int b  = bid >> 6;
    int tid = threadIdx.x;
    int w = tid >> 6, l = tid & 63;
    int mt = w & 1, nt = w >> 1;

    f32x4 acc = {0.f, 0.f, 0.f, 0.f};
    const char* xc = (const char*)xs;

    for (int half = 0; half < 2; ++half) {
        __syncthreads();
        // stage halo slab: rows oy-1..oy+1, cols -1..66, c-half (128 ch)
        for (int e = tid; e < 3 * 68 * 16; e += 512) {
            int cg = e & 15;
            int j  = (e >> 4) % 68;
            int ry = e / (68 * 16);
            int yi = oy + ry - 1, xi = j - 1;
            uint4 v = make_uint4(0u, 0u, 0u, 0u);
            if ((unsigned)yi < (unsigned)H_IMG && (unsigned)xi < (unsigned)W_IMG)
                v = *(const uint4*)(xT + (((size_t)(b * H_IMG + yi) * W_IMG + xi) * C_IN
                                          + half * 128 + cg * 8));
            *(uint4*)((char*)xs + SW(j, (ry * 68 + j) * 256 + cg * 16)) = v;
        }
        __syncthreads();
        for (int tap = 0; tap < NK; ++tap) {
            int dy = tap / 3, dx = tap % 3 - 1;
            #pragma unroll
            for (int ks = 0; ks < 4; ++ks) {
                s16x8 af = *(const s16x8*)(wA + (((size_t)tap * 32 + mt * 16 + (l & 15)) * C_IN
                                                 + half * 128 + ks * 32 + (l >> 4) * 8));
                int j = nt * 16 + (l & 15) + dx + 1;
                s16x8 bf = *(const s16x8*)(xc + SW(j, (dy * 68 + j) * 256 + ks * 64 + (l >> 4) * 16));
                acc = __builtin_amdgcn_mfma_f32_16x16x32_bf16(af, bf, acc, 0, 0, 0);
            }
        }
    }

    int ox = nt * 16 + (l & 15);
    #pragma unroll
    for (int r = 0; r < 4; ++r) {
        int co = mt * 16 + (l >> 4) * 4 + r;
        if (co < NOFF)
            off[(((size_t)b * NOFF + co) * H_IMG + oy) * W_IMG + ox] = acc[r] + b_off[co];
    }
}

// ---------------------------------------------------------------------------
// K2 v3: fused bilinear sampling + grouped conv via MFMA, channel-last gather.
// block=(b,g,oy), 256 thr = 4 waves.  Corner loads = contiguous 16B (8 ch).
// A-frags straight from L2-resident wB2 (no LDS).  bS same as r4 (0 conflicts).
// ---------------------------------------------------------------------------
__global__ __launch_bounds__(256)
void deform_main_mfma(const unsigned short* __restrict__ xT, const float* __restrict__ off,
                      const unsigned short* __restrict__ wB2, float* __restrict__ out) {
    __shared__ int4   sidx[NK * 64];   // 9216 B  (clamped position index iy*64+ix)
    __shared__ float4 swt [NK * 64];   // 9216 B  (validity-masked bilinear weights)
    __shared__ uint4  bS[512];         // 8 KB    B [64ox][64i] bf16, swizzled

    int bid = blockIdx.x;
    int oy = bid & 63;
    int g  = (bid >> 6) & 3;
    int b  = bid >> 8;
    int tid = threadIdx.x;
    int w  = tid >> 6;
    int l  = tid & 63;

    // ---- Phase A: sampling metadata (fp32) ----
    for (int e = tid; e < NK * 64; e += 256) {
        int k = e >> 6, ox = e & 63;
        int ki = k / 3, kj = k % 3;
        float offy = off[((size_t)b * NOFF + 2 * k)     * HWSZ + oy * W_IMG + ox];
        float offx = off[((size_t)b * NOFF + 2 * k + 1) * HWSZ + oy * W_IMG + ox];
        float py = (float)(oy - 1 + ki) + offy;
        float px = (float)(ox - 1 + kj) + offx;
        float y0 = floorf(py), x0 = floorf(px);
        float wy1 = py - y0, wx1 = px - x0;
        float wy0 = 1.f - wy1, wx0 = 1.f - wx1;
        float y1 = y0 + 1.f, x1 = x0 + 1.f;
        bool vy0 = (y0 >= 0.f) && (y0 <= 63.f);
        bool vy1 = (y1 >= 0.f) && (y1 <= 63.f);
        bool vx0 = (x0 >= 0.f) && (x0 <= 63.f);
        bool vx1 = (x1 >= 0.f) && (x1 <= 63.f);
        int iy0 = (int)fminf(fmaxf(y0, 0.f), 63.f);
        int iy1 = (int)fminf(fmaxf(y1, 0.f), 63.f);
        int ix0 = (int)fminf(fmaxf(x0, 0.f), 63.f);
        int ix1 = (int)fminf(fmaxf(x1, 0.f), 63.f);
        sidx[e] = make_int4(iy0 * W_IMG + ix0, iy0 * W_IMG + ix1,
                            iy1 * W_IMG + ix0, iy1 * W_IMG + ix1);
        swt[e] = make_float4(vy0 && vx0 ? wy0 * wx0 : 0.f,
                             vy0 && vx1 ? wy0 * wx1 : 0.f,
                             vy1 && vx0 ? wy1 * wx0 : 0.f,
                             vy1 && vx1 ? wy1 * wx1 : 0.f);
    }

    int p_st = tid & 63;          // staging column (ox)
    int cg   = tid >> 6;          // staging i-group (16 i's)
    const char* xb = (const char*)xT + ((size_t)b << 21) + ((size_t)g << 7); // b*4096*512 + g*128
    const char* bC = (const char*)bS;

    f32x4 acc[2][2] = {{{0.f,0.f,0.f,0.f},{0.f,0.f,0.f,0.f}},
                       {{0.f,0.f,0.f,0.f},{0.f,0.f,0.f,0.f}}};

    for (int k = 0; k < NK; ++k) {
        // prefetch A-frags (global, L2-resident) — overlaps barrier + gather
        s16x8 af[2][2];
        const unsigned short* wk = wB2 + ((size_t)(g * NK + k) * CG) * CG;
        #pragma unroll
        for (int i2 = 0; i2 < 2; ++i2) {
            int ra = (2 * (w & 1) + i2) * 16 + (l & 15);
            #pragma unroll
            for (int ks = 0; ks < 2; ++ks)
                af[i2][ks] = *(const s16x8*)(wk + ra * CG + ks * 32 + (l >> 4) * 8);
        }
        __syncthreads();   // prev MFMA reads done; Phase A done (k=0)
        // gather: 2 subgroups of 8 channels; 4 corners x 16B contiguous loads
        {
            int4   p4  = sidx[k * 64 + p_st];
            float4 wt4 = swt [k * 64 + p_st];
            #pragma unroll
            for (int e = 0; e < 2; ++e) {
                int cb = cg * 32 + e * 16;   // byte offset within this g's 128B c-slice
                s16x8 va = *(const s16x8*)(xb + (size_t)p4.x * 512 + cb);
                s16x8 vb = *(const s16x8*)(xb + (size_t)p4.y * 512 + cb);
                s16x8 vc = *(const s16x8*)(xb + (size_t)p4.z * 512 + cb);
                s16x8 vd = *(const s16x8*)(xb + (size_t)p4.w * 512 + cb);
                unsigned short us[8];
                #pragma unroll
                for (int j = 0; j < 8; ++j) {
                    float v = wt4.x * bf2f((unsigned short)va[j]);
                    v = fmaf(wt4.y, bf2f((unsigned short)vb[j]), v);
                    v = fmaf(wt4.z, bf2f((unsigned short)vc[j]), v);
                    v = fmaf(wt4.w, bf2f((unsigned short)vd[j]), v);
                    us[j] = f2bf(v);
                }
                uint4 q = make_uint4(pk(us[0],us[1]), pk(us[2],us[3]),
                                     pk(us[4],us[5]), pk(us[6],us[7]));
                *(uint4*)((char*)bS + SW(p_st, p_st * 128 + cb)) = q;
            }
        }
        __syncthreads();
        // MFMA
        #pragma unroll
        for (int ks = 0; ks < 2; ++ks) {
            int kb = ks * 64 + (l >> 4) * 16;
            s16x8 bfr[2];
            #pragma unroll
            for (int j2 = 0; j2 < 2; ++j2) {
                int rb = (2 * (w >> 1) + j2) * 16 + (l & 15);
                bfr[j2] = *(const s16x8*)(bC + SW(rb, rb * 128 + kb));
            }
            #pragma unroll
            for (int i2 = 0; i2 < 2; ++i2)
                #pragma unroll
                for (int j2 = 0; j2 < 2; ++j2)
                    acc[i2][j2] = __builtin_amdgcn_mfma_f32_16x16x32_bf16(af[i2][ks], bfr[j2], acc[i2][j2], 0, 0, 0);
        }
    }

    // epilogue: D row m=(l>>4)*4+r (o), col n=l&15 (ox)
    #pragma unroll
    for (int i2 = 0; i2 < 2; ++i2) {
        int o0 = (2 * (w & 1) + i2) * 16 + (l >> 4) * 4;
        #pragma unroll
        for (int j2 = 0; j2 < 2; ++j2) {
            int px = (2 * (w >> 1) + j2) * 16 + (l & 15);
            float* ob = out + ((((size_t)b * C_IN + g * CG + o0) * H_IMG + oy) * W_IMG) + px;
            #pragma unroll
            for (int r = 0; r < 4; ++r)
                ob[(size_t)r * HWSZ] = acc[i2][j2][r];
        }
    }
}

// ---------------------------------------------------------------------------
extern "C" void kernel_launch(void* const* d_in, const int* in_sizes, int n_in,
                              void* d_out, int out_size, void* d_ws, size_t ws_size,
                              hipStream_t stream) {
    const float* x        = (const float*)d_in[0];
    const float* w_off    = (const float*)d_in[1];
    const float* b_off    = (const float*)d_in[2];
    const float* w_deform = (const float*)d_in[3];
    float* out = (float*)d_out;

    // ws layout (bytes): off fp32 [1179648] | wA bf16 [147456] | wB2 bf16 [294912]
    //                    | xT bf16 [8388608]   (total ~9.6 MB)
    float* off = (float*)d_ws;
    unsigned short* wA  = (unsigned short*)((char*)d_ws + 1179648);
    unsigned short* wB2 = wA + NK * 32 * C_IN;
    unsigned short* xT  = wB2 + NG * NK * CG * CG;

    prep_woff_kernel<<<(NK * 32 * C_IN + 255) / 256, 256, 0, stream>>>(w_off, wA);
    prep_wdef_kernel<<<(NG * NK * CG * CG + 255) / 256, 256, 0, stream>>>(w_deform, wB2);
    prep_xT_kernel<<<B_SZ * H_IMG, 256, 0, stream>>>(x, xT);
    off_conv_mfma<<<B_SZ * H_IMG, 512, 0, stream>>>(xT, wA, b_off, off);
    deform_main_mfma<<<B_SZ * NG * H_IMG, 256, 0, stream>>>(xT, off, wB2, out);
}